// Round 2
// baseline (354.486 us; speedup 1.0000x reference)
//
#include <hip/hip_runtime.h>
#include <hip/hip_bf16.h>
#include <math.h>

// Problem constants
#define Bc 2
#define Lc 1024
#define Dc 768
#define Hc 12
#define DHc 64
#define BLD (Bc * Lc * Dc)   // 1,572,864
#define Mrows (Bc * Lc)      // 2048
#define CS 64                // attention chunk size
#define NC (Lc / CS)         // 16 chunks
#define STATE (DHc * DHc + DHc)  // 4160 floats per (b,h,chunk) state

// ---------------------------------------------------------------------------
// LayerNorm: one block per row (B*L rows of D=768), 256 threads, 3 elems/thread
// ---------------------------------------------------------------------------
__global__ __launch_bounds__(256) void ln_kernel(const float* __restrict__ x,
                                                 const float* __restrict__ g,
                                                 const float* __restrict__ b,
                                                 float* __restrict__ xn) {
    const int row = blockIdx.x;
    const float* xr = x + (size_t)row * Dc;
    float v[3];
    float s = 0.f, ss = 0.f;
#pragma unroll
    for (int i = 0; i < 3; ++i) {
        v[i] = xr[threadIdx.x + i * 256];
        s += v[i];
        ss += v[i] * v[i];
    }
#pragma unroll
    for (int off = 32; off > 0; off >>= 1) {
        s  += __shfl_down(s, off, 64);
        ss += __shfl_down(ss, off, 64);
    }
    __shared__ float sw[2][4];
    const int wave = threadIdx.x >> 6;
    const int lane = threadIdx.x & 63;
    if (lane == 0) { sw[0][wave] = s; sw[1][wave] = ss; }
    __syncthreads();
    s  = sw[0][0] + sw[0][1] + sw[0][2] + sw[0][3];
    ss = sw[1][0] + sw[1][1] + sw[1][2] + sw[1][3];
    const float mu = s * (1.f / Dc);
    const float var = ss * (1.f / Dc) - mu * mu;
    const float rstd = rsqrtf(var + 1e-5f);
    float* xo = xn + (size_t)row * Dc;
#pragma unroll
    for (int i = 0; i < 3; ++i) {
        const int c = threadIdx.x + i * 256;
        xo[c] = (v[i] - mu) * rstd * g[c] + b[c];
    }
}

// ---------------------------------------------------------------------------
// fp32 GEMM: C[M,N] = A[M,K] @ W[K,N] + bias
// EPI: 0 = none, 1 = sigmoid, 2 = qkv featurize (elu(q)+1 | elu(k*gate)+1 | v)
// 64x64 tile, BK=16, 256 threads, 4x4 per thread. M,N,K multiples of tile.
// ---------------------------------------------------------------------------
template <int EPI>
__global__ __launch_bounds__(256) void gemm_kernel(const float* __restrict__ A,
                                                   const float* __restrict__ W,
                                                   const float* __restrict__ bias,
                                                   const float* __restrict__ gate,
                                                   float* __restrict__ C,
                                                   int M, int N, int K) {
    __shared__ float As[16][68];  // [k][row], pad 68 keeps float4 16B-aligned
    __shared__ float Ws[16][68];  // [k][col]
    const int row0 = blockIdx.y * 64;
    const int col0 = blockIdx.x * 64;
    const int tid = threadIdx.x;
    const int tr = tid >> 4;   // 0..15
    const int tc = tid & 15;   // 0..15

    const int lr  = tid >> 2;        // 0..63 A-tile row
    const int lk4 = (tid & 3) * 4;   // 0/4/8/12 k offset
    const int wk  = tid >> 4;        // 0..15 W-tile k row
    const int wc4 = (tid & 15) * 4;  // 0..60 col offset

    float acc[4][4];
#pragma unroll
    for (int i = 0; i < 4; ++i)
#pragma unroll
        for (int j = 0; j < 4; ++j) acc[i][j] = 0.f;

    for (int k0 = 0; k0 < K; k0 += 16) {
        const float4 a4 = *reinterpret_cast<const float4*>(
            &A[(size_t)(row0 + lr) * K + k0 + lk4]);
        As[lk4 + 0][lr] = a4.x;
        As[lk4 + 1][lr] = a4.y;
        As[lk4 + 2][lr] = a4.z;
        As[lk4 + 3][lr] = a4.w;
        const float4 w4 = *reinterpret_cast<const float4*>(
            &W[(size_t)(k0 + wk) * N + col0 + wc4]);
        *reinterpret_cast<float4*>(&Ws[wk][wc4]) = w4;
        __syncthreads();
#pragma unroll
        for (int k = 0; k < 16; ++k) {
            const float4 av = *reinterpret_cast<const float4*>(&As[k][tr * 4]);
            const float4 wv = *reinterpret_cast<const float4*>(&Ws[k][tc * 4]);
            const float a[4] = {av.x, av.y, av.z, av.w};
            const float w[4] = {wv.x, wv.y, wv.z, wv.w};
#pragma unroll
            for (int i = 0; i < 4; ++i)
#pragma unroll
                for (int j = 0; j < 4; ++j) acc[i][j] = fmaf(a[i], w[j], acc[i][j]);
        }
        __syncthreads();
    }

#pragma unroll
    for (int i = 0; i < 4; ++i) {
        const size_t r = row0 + tr * 4 + i;
        float vals[4];
#pragma unroll
        for (int j = 0; j < 4; ++j) {
            const int c = col0 + tc * 4 + j;
            float v = acc[i][j] + bias[c];
            if (EPI == 1) v = 1.f / (1.f + expf(-v));
            if (EPI == 2) {
                // cols [0,768): q -> elu+1 ; [768,1536): k*gate -> elu+1 ; rest: v
                if (c < 2 * Dc) {
                    float t = v;
                    if (c >= Dc) t *= gate[r * Dc + (c - Dc)];
                    v = t > 0.f ? t + 1.f : expf(t);
                }
            }
            vals[j] = v;
        }
        float4 o = {vals[0], vals[1], vals[2], vals[3]};
        *reinterpret_cast<float4*>(&C[r * N + col0 + tc * 4]) = o;
    }
}

// ---------------------------------------------------------------------------
// Phase A: per (b,h,chunk) compute chunk-local sum of k_f (x) v  (64x64)
// and chunk-local sum of k_f (64). qkv already featurized.
// Thread (g4=tid>>6, e=tid&63) owns S[d0+i][e], d0=g4*16.
// ---------------------------------------------------------------------------
__global__ __launch_bounds__(256) void chunk_sum_kernel(const float* __restrict__ qkv,
                                                        float* __restrict__ buf) {
    const int c  = blockIdx.x;   // chunk
    const int bh = blockIdx.y;   // b*H + h
    const int b = bh / Hc, h = bh % Hc;
    const int tid = threadIdx.x;
    const int e  = tid & 63;
    const int g4 = tid >> 6;
    const int d0 = g4 * 16;

    __shared__ float sk[CS][DHc];
    __shared__ float sv[CS][DHc];

    const size_t row0 = (size_t)b * Lc + c * CS;
#pragma unroll
    for (int j = 0; j < 4; ++j) {
        const int fi = j * 256 + tid;            // float4 index, 1024 total
        const int l = fi >> 4, c4 = (fi & 15) * 4;
        const size_t gbase = (row0 + l) * (3 * Dc) + h * DHc + c4;
        *reinterpret_cast<float4*>(&sk[l][c4]) =
            *reinterpret_cast<const float4*>(&qkv[gbase + Dc]);
        *reinterpret_cast<float4*>(&sv[l][c4]) =
            *reinterpret_cast<const float4*>(&qkv[gbase + 2 * Dc]);
    }
    __syncthreads();

    float S[16];
#pragma unroll
    for (int i = 0; i < 16; ++i) S[i] = 0.f;
    float ksum = 0.f;
    for (int l = 0; l < CS; ++l) {
        const float vv = sv[l][e];
#pragma unroll
        for (int i = 0; i < 16; ++i) S[i] = fmaf(sk[l][d0 + i], vv, S[i]);
        if (g4 == 0) ksum += sk[l][e];
    }
    float* out = buf + ((size_t)bh * NC + c) * STATE;
#pragma unroll
    for (int i = 0; i < 16; ++i) out[(d0 + i) * DHc + e] = S[i];
    if (g4 == 0) out[DHc * DHc + e] = ksum;
}

// ---------------------------------------------------------------------------
// Phase B: in-place EXCLUSIVE prefix scan over the NC chunk states per (b,h).
// buf layout: [B*H][NC][STATE]. One block per (b,h).
// ---------------------------------------------------------------------------
__global__ __launch_bounds__(256) void scan_kernel(float* __restrict__ buf) {
    const int bh = blockIdx.x;
    float* base = buf + (size_t)bh * NC * STATE;
    const int tid = threadIdx.x;
    float r[17];
#pragma unroll
    for (int j = 0; j < 17; ++j) r[j] = 0.f;
    for (int c = 0; c < NC; ++c) {
        float* p = base + (size_t)c * STATE;
#pragma unroll
        for (int j = 0; j < 17; ++j) {
            const int idx = j * 256 + tid;
            if (idx < STATE) {
                const float cur = p[idx];
                p[idx] = r[j];          // exclusive prefix
                r[j] += cur;
            }
        }
    }
}

// ---------------------------------------------------------------------------
// Phase C: per (b,h,chunk) run the 64-step recurrence seeded with the
// exclusive prefix state; write attn outputs.
// ---------------------------------------------------------------------------
__global__ __launch_bounds__(256) void chunk_out_kernel(const float* __restrict__ qkv,
                                                        const float* __restrict__ buf,
                                                        float* __restrict__ attn) {
    const int c  = blockIdx.x;
    const int bh = blockIdx.y;
    const int b = bh / Hc, h = bh % Hc;
    const int tid = threadIdx.x;
    const int e  = tid & 63;
    const int g4 = tid >> 6;
    const int d0 = g4 * 16;

    __shared__ float sq[CS][DHc], sk[CS][DHc], sv[CS][DHc];
    __shared__ float rn[4][DHc], rd[4][DHc];

    const size_t row0 = (size_t)b * Lc + c * CS;
#pragma unroll
    for (int j = 0; j < 4; ++j) {
        const int fi = j * 256 + tid;
        const int l = fi >> 4, c4 = (fi & 15) * 4;
        const size_t gbase = (row0 + l) * (3 * Dc) + h * DHc + c4;
        *reinterpret_cast<float4*>(&sq[l][c4]) =
            *reinterpret_cast<const float4*>(&qkv[gbase]);
        *reinterpret_cast<float4*>(&sk[l][c4]) =
            *reinterpret_cast<const float4*>(&qkv[gbase + Dc]);
        *reinterpret_cast<float4*>(&sv[l][c4]) =
            *reinterpret_cast<const float4*>(&qkv[gbase + 2 * Dc]);
    }
    const float* P = buf + ((size_t)bh * NC + c) * STATE;
    float S[16], kc[16];
#pragma unroll
    for (int i = 0; i < 16; ++i) {
        S[i]  = P[(d0 + i) * DHc + e];       // coalesced over e
        kc[i] = P[DHc * DHc + d0 + i];       // uniform broadcast
    }
    __syncthreads();

    for (int l = 0; l < CS; ++l) {
        const float vv = sv[l][e];
        float num = 0.f, den = 0.f;
#pragma unroll
        for (int i = 0; i < 16; ++i) {
            const float kd = sk[l][d0 + i];  // wave-uniform LDS broadcast
            const float qd = sq[l][d0 + i];
            S[i] = fmaf(kd, vv, S[i]);
            num  = fmaf(qd, S[i], num);
            kc[i] += kd;
            den  = fmaf(qd, kc[i], den);
        }
        rn[g4][e] = num;
        rd[g4][e] = den;
        __syncthreads();
        if (g4 == 0) {
            const float n  = rn[0][e] + rn[1][e] + rn[2][e] + rn[3][e];
            const float dd = rd[0][e] + rd[1][e] + rd[2][e] + rd[3][e] + 1e-6f;
            attn[(row0 + l) * Dc + h * DHc + e] = n / dd;
        }
        __syncthreads();  // WAR: protect rn/rd before next iteration's write
    }
}

// ---------------------------------------------------------------------------
extern "C" void kernel_launch(void* const* d_in, const int* in_sizes, int n_in,
                              void* d_out, int out_size, void* d_ws, size_t ws_size,
                              hipStream_t stream) {
    const float* x      = (const float*)d_in[0];
    const float* W_qkv  = (const float*)d_in[1];
    const float* b_qkv  = (const float*)d_in[2];
    const float* W_gate = (const float*)d_in[3];
    const float* b_gate = (const float*)d_in[4];
    const float* W_proj = (const float*)d_in[5];
    const float* b_proj = (const float*)d_in[6];
    const float* ln_g   = (const float*)d_in[7];
    const float* ln_b   = (const float*)d_in[8];

    float* out_proj = (float*)d_out;             // (B,L,D)
    float* out_gate = out_proj + (size_t)BLD;    // (B,L,D)

    float* ws   = (float*)d_ws;
    float* qkv  = ws;                       // 3*BLD (featurized q_f|k_f|v)
    float* xn   = ws + (size_t)3 * BLD;     // BLD; dead after qkv GEMM
    float* attn = xn;                       // alias
    float* cbuf = ws + (size_t)4 * BLD;     // B*H*NC*STATE = 1,597,440 floats

    // 1) LayerNorm
    ln_kernel<<<Mrows, 256, 0, stream>>>(x, ln_g, ln_b, xn);
    // 2) gate = sigmoid(x @ W_gate + b_gate)  (needed by qkv epilogue)
    gemm_kernel<1><<<dim3(Dc / 64, Mrows / 64), 256, 0, stream>>>(
        x, W_gate, b_gate, nullptr, out_gate, Mrows, Dc, Dc);
    // 3) qkv = xn @ W_qkv + b_qkv, epilogue: q->elu+1, k->elu(k*gate)+1, v raw
    gemm_kernel<2><<<dim3(3 * Dc / 64, Mrows / 64), 256, 0, stream>>>(
        xn, W_qkv, b_qkv, out_gate, qkv, Mrows, 3 * Dc, Dc);
    // 4) Phase A: chunk-local KV / Ksum
    chunk_sum_kernel<<<dim3(NC, Bc * Hc), 256, 0, stream>>>(qkv, cbuf);
    // 5) Phase B: exclusive prefix scan across chunks
    scan_kernel<<<Bc * Hc, 256, 0, stream>>>(cbuf);
    // 6) Phase C: within-chunk recurrence + output
    chunk_out_kernel<<<dim3(NC, Bc * Hc), 256, 0, stream>>>(qkv, cbuf, attn);
    // 7) out = attn @ W_proj + b_proj
    gemm_kernel<0><<<dim3(Dc / 64, Mrows / 64), 256, 0, stream>>>(
        attn, W_proj, b_proj, nullptr, out_proj, Mrows, Dc, Dc);
}